// Round 1
// 90.968 us; speedup vs baseline: 1.2202x; 1.2202x over previous
//
#include <hip/hip_runtime.h>
#include <math.h>

// Canny, round 9: algebraic short-circuit + verified fallback.
//
// Key fact: with gauss weights positive and summing to 1, blurred bl ∈ [0,1]
// whenever x ∈ [0,1] (zero-padding only shrinks the range). Sobel/8 on a
// [0,1] field gives |gx|,|gy| <= 0.5, so mag = sqrt(gx^2+gy^2+1e-9) <=
// sqrt(0.5+1e-9) ~= 0.70711 at EVERY pixel (edge-replicate included).
// Therefore if low_threshold >= 0.7072, where(suppressed>=t,...) picks 1e-9
// everywhere and out == sigmoid(1e-9) == 0.5f bit-exactly.
//
// Fast path: per strip, load exactly the input rows that influence this
// strip's outputs (rows R0-4 .. R0+SH+3, the same bytes the full path reads),
// validate x in [0,1] (NaN fails the compares -> fallback), check t>=0.7072
// wave-uniformly, and store the constant. Otherwise run the previous,
// harness-verified full pipeline unchanged.

typedef float v2f __attribute__((ext_vector_type(2)));

#define HDIM 512
#define WDIM 512
#define PLANE (HDIM * WDIM)
#define SH   8
#define NSTR (HDIM / SH)   // 64 strips
#define NGRP 5             // 5 x 112 = 560 >= 512
#define GW   112

__device__ __forceinline__ float shfl1(float v, int src) {
    return __shfl(v, src, 64);
}

// ---- fast-path range validation: all influencing inputs in [0,1]? ----
__device__ __forceinline__ int unit_range_ok(
    const float* __restrict__ xb0, int R0, int c0, int colok)
{
    int ok = 1;
    #pragma unroll
    for (int r = 0; r < SH + 8; ++r) {          // rows R0-4 .. R0+SH+3
        const int ri = R0 - 4 + r;
        const int rowok = ((unsigned)ri < (unsigned)HDIM);
        #pragma unroll
        for (int c = 0; c < 3; ++c) {
            v2f v = {0.5f, 0.5f};               // neutral for masked lanes
            if (rowok & colok)
                v = *(const v2f*)(xb0 + c * PLANE + ri * WDIM + c0);
            ok &= (int)(v.x >= 0.f) & (int)(v.x <= 1.f)
                & (int)(v.y >= 0.f) & (int)(v.y <= 1.f);
        }
    }
    return ok;
}

template<bool RE, bool CE>
__device__ __forceinline__ void run(
    const float* __restrict__ xb0, float t, float* __restrict__ out,
    int b, int R0, int c0, int lane)
{
    const bool colok = !CE || ((unsigned)c0 < (unsigned)WDIM);

    const float w0 = 0.05448868454964294f;   // gauss5(sigma=1)/sum
    const float w1 = 0.24420134200323332f;
    const float w2 = 0.4026199468942475f;
    const float T1c = 0.41421356237309503f;  // tan(pi/8)
    const float T3c = 2.414213562373095f;    // tan(3pi/8)

    auto ld2 = [&](int c, int ri) -> v2f {
        if ((CE && !colok) || (RE && (unsigned)ri >= (unsigned)HDIM)) {
            v2f z = {0.f, 0.f};
            return z;
        }
        return *(const v2f*)(xb0 + c * PLANE + ri * WDIM + c0);
    };
    // immediate horizontal blur (prologue only)
    auto hb2 = [&](v2f v) -> v2f {
        v2f L, R;
        L.x = shfl1(v.x, lane - 1); L.y = shfl1(v.y, lane - 1);
        R.x = shfl1(v.x, lane + 1); R.y = shfl1(v.y, lane + 1);
        v2f p = {L.y, v.x};
        v2f q = {v.y, R.x};
        return w0 * (L + R) + w1 * (p + q) + w2 * v;
    };
    auto dirof = [&](float gx, float gy) -> int {
        const float gys = (gy == 0.f) ? 1e-9f : gy;
        const float sg  = (gys > 0.f) ? 1.f : -1.f;
        const float gxs = gx * sg;            // a>=c  <=>  gxs >= c*|gys|
        const float gya = fabsf(gys);
        const float a3 = T3c * gya, a1 = T1c * gya;
        return (gxs >= a3 || gxs < -a3) ? 2
             : (gxs >= a1) ? 1
             : (gxs >= -a1) ? 0 : 3;
    };

    // ---- rolling state at top of iteration m ----
    v2f xw0[3], xw1[3], xw2[3], xw3[3];   // x rows m+1..m+4
    v2f xn1[3], xn2[3];                   // x rows m+5, m+6 (in flight)
    v2f vbO[3];                           // vb(m+2) own value
    float vbLx[3], vbLy[3], vbRx[3], vbRy[3];   // its shfls (ready)
    v2f blB[3], blC[3];                   // bl rows m, m+1
    v2f ttO[3], uuO[3];                   // sobel col-sums for row m
    float ttL[3], ttR[3], uuL[3], uuR[3]; // their shfls (ready)
    v2f mg0 = {0.f, 0.f}, mg1 = {0.f, 0.f}, mg2 = {0.f, 0.f}; // mag m-3..m-1
    float s0l = 0.f, s0r = 0.f, s1l = 0.f, s1r = 0.f, s2l = 0.f, s2r = 0.f;
    int d1x = 0, d1y = 0, d2x = 0, d2y = 0;  // dir rows m-2, m-1

    // ---- prologue: establish state for m = R0-1 ----
    #pragma unroll
    for (int c = 0; c < 3; ++c) {
        v2f p0 = ld2(c, R0 - 4), p1 = ld2(c, R0 - 3), p2 = ld2(c, R0 - 2);
        v2f p3 = ld2(c, R0 - 1), p4 = ld2(c, R0),     p5 = ld2(c, R0 + 1);
        v2f p6 = ld2(c, R0 + 2), p7 = ld2(c, R0 + 3);
        v2f vA = w0 * (p0 + p4) + w1 * (p1 + p3) + w2 * p2;  // vb(R0-2)
        v2f vB = w0 * (p1 + p5) + w1 * (p2 + p4) + w2 * p3;  // vb(R0-1)
        v2f vC = w0 * (p2 + p6) + w1 * (p3 + p5) + w2 * p4;  // vb(R0)
        v2f vD = w0 * (p3 + p7) + w1 * (p4 + p6) + w2 * p5;  // vb(R0+1)
        v2f blA = hb2(vA);          // bl(R0-2), prologue-only
        blB[c] = hb2(vB);           // bl(R0-1)
        blC[c] = hb2(vC);           // bl(R0)
        vbO[c] = vD;                // vb(R0+1): issue shfls, combine at m=R0-1
        vbLx[c] = shfl1(vD.x, lane - 1); vbLy[c] = shfl1(vD.y, lane - 1);
        vbRx[c] = shfl1(vD.x, lane + 1); vbRy[c] = shfl1(vD.y, lane + 1);
        xw0[c] = p4; xw1[c] = p5; xw2[c] = p6; xw3[c] = p7;
        xn1[c] = ld2(c, R0 + 4);
        xn2[c] = ld2(c, R0 + 5);
        // tt/uu for sobel row R0-1 (row -1 of s=0 strips is masked later)
        v2f bm = blA, b0 = blB[c], bp = blC[c];
        ttO[c] = bm + 2.f * b0 + bp;
        uuO[c] = bp - bm;
        ttL[c] = shfl1(ttO[c].y, lane - 1); ttR[c] = shfl1(ttO[c].x, lane + 1);
        uuL[c] = shfl1(uuO[c].y, lane - 1); uuR[c] = shfl1(uuO[c].x, lane + 1);
    }

    auto nms_store = [&](int row) {
        // element .x (col c0): left neighbor = s*l, right = own .y
        float n1x = (d1x == 0) ? mg0.x : (d1x == 1) ? s0l
                  : (d1x == 2) ? s1l   : mg0.y;
        float n2x = (d1x == 0) ? mg2.x : (d1x == 1) ? mg2.y
                  : (d1x == 2) ? mg1.y : s2l;
        // element .y (col c0+1): left = own .x, right = s*r
        float n1y = (d1y == 0) ? mg0.y : (d1y == 1) ? mg0.x
                  : (d1y == 2) ? mg1.x : s0r;
        float n2y = (d1y == 0) ? mg2.y : (d1y == 1) ? s2r
                  : (d1y == 2) ? s1r   : mg2.x;
        float sx = (mg1.x >= n1x && mg1.x >= n2x) ? mg1.x : 0.f;
        float sy = (mg1.y >= n1y && mg1.y >= n2y) ? mg1.y : 0.f;
        float vx = (sx >= t) ? sx : 1e-9f;
        float vy = (sy >= t) ? sy : 1e-9f;
        v2f o;
        o.x = __builtin_amdgcn_rcpf(1.f + __expf(-vx));
        o.y = __builtin_amdgcn_rcpf(1.f + __expf(-vy));
        bool doit = (lane >= 4 && lane < 60);
        if (CE) doit = doit && colok;
        if (doit)
            *(v2f*)&out[((size_t)b * HDIM + row) * WDIM + c0] = o;
    };

    // ---- main loop (trip count SH+2 = 10, constant) ----
    #pragma unroll 2
    for (int m = R0 - 1; m <= R0 + SH; ++m) {
        // a: prefetch ring — consume x(m+5), issue x(m+7)
        v2f xn[3], blD[3];
        #pragma unroll
        for (int c = 0; c < 3; ++c) {
            xn[c]  = xn1[c];
            xn1[c] = xn2[c];
            xn2[c] = ld2(c, m + 7);
        }

        // b: store row m-2 (all shfl inputs ready since last iteration)
        if (m >= R0 + 2) nms_store(m - 2);

        // c: combine bl(m+2) from vb(m+2) own + ready shfls
        #pragma unroll
        for (int c = 0; c < 3; ++c) {
            v2f L = {vbLx[c], vbLy[c]}, Rr = {vbRx[c], vbRy[c]};
            v2f p = {L.y, vbO[c].x};
            v2f q = {vbO[c].y, Rr.x};
            blD[c] = w0 * (L + Rr) + w1 * (p + q) + w2 * vbO[c];
        }

        // d: sobel row m from ready tt/uu + shfls
        v2f best = {-1.f, -1.f}, bgx = {0.f, 0.f}, bgy = {0.f, 0.f};
        #pragma unroll
        for (int c = 0; c < 3; ++c) {
            float tly = ttL[c], trx = ttR[c], uly = uuL[c], urx = uuR[c];
            if (CE) {                              // col edge-replicate
                if (c0 == 0)            { tly = ttO[c].x; uly = uuO[c].x; }
                if (c0 + 1 == WDIM - 1) { trx = ttO[c].y; urx = uuO[c].y; }
            }
            v2f gA = {ttO[c].y, trx}, gB = {tly, ttO[c].x};
            v2f gxv = 0.125f * (gA - gB);
            v2f hA = {uly, uuO[c].x}, hB = {uuO[c].y, urx};
            v2f gyv = 0.125f * (hA + 2.f * uuO[c] + hB);
            v2f m2v = gxv * gxv + gyv * gyv;
            if (m2v.x > best.x) { best.x = m2v.x; bgx.x = gxv.x; bgy.x = gyv.x; }
            if (m2v.y > best.y) { best.y = m2v.y; bgx.y = gxv.y; bgy.y = gyv.y; }
        }
        v2f mag2v;
        mag2v.x = __builtin_amdgcn_sqrtf(best.x + 1e-9f);
        mag2v.y = __builtin_amdgcn_sqrtf(best.y + 1e-9f);
        if (RE && (unsigned)m >= (unsigned)HDIM) { mag2v.x = 0.f; mag2v.y = 0.f; }
        if (CE && !colok)                        { mag2v.x = 0.f; mag2v.y = 0.f; }
        const int dnx = dirof(bgx.x, bgy.x);
        const int dny = dirof(bgx.y, bgy.y);

        // e: build tt/uu for row m+1, issue their shfls (consumed next iter)
        #pragma unroll
        for (int c = 0; c < 3; ++c) {
            v2f bm = blB[c], b0 = blC[c], bp = blD[c];
            if (RE) {                              // row edge-replicate
                if (m + 1 == 0)        bm = b0;
                if (m + 1 == HDIM - 1) bp = b0;
            }
            ttO[c] = bm + 2.f * b0 + bp;
            uuO[c] = bp - bm;
            ttL[c] = shfl1(ttO[c].y, lane - 1); ttR[c] = shfl1(ttO[c].x, lane + 1);
            uuL[c] = shfl1(uuO[c].y, lane - 1); uuR[c] = shfl1(uuO[c].x, lane + 1);
        }

        // f: build vb(m+3), issue its shfls; roll x window
        #pragma unroll
        for (int c = 0; c < 3; ++c) {
            v2f vbN = w0 * (xw0[c] + xn[c]) + w1 * (xw1[c] + xw3[c])
                    + w2 * xw2[c];
            vbO[c] = vbN;
            vbLx[c] = shfl1(vbN.x, lane - 1); vbLy[c] = shfl1(vbN.y, lane - 1);
            vbRx[c] = shfl1(vbN.x, lane + 1); vbRy[c] = shfl1(vbN.y, lane + 1);
            xw0[c] = xw1[c]; xw1[c] = xw2[c]; xw2[c] = xw3[c]; xw3[c] = xn[c];
        }

        // g: issue NMS shfls for next store (row m-1)
        s0l = shfl1(mg1.y, lane - 1);   s0r = shfl1(mg1.x, lane + 1);
        s1l = shfl1(mg2.y, lane - 1);   s1r = shfl1(mg2.x, lane + 1);
        s2l = shfl1(mag2v.y, lane - 1); s2r = shfl1(mag2v.x, lane + 1);

        // h: rolls (register renames under unroll)
        blB[0] = blC[0]; blC[0] = blD[0];
        blB[1] = blC[1]; blC[1] = blD[1];
        blB[2] = blC[2]; blC[2] = blD[2];
        mg0 = mg1; mg1 = mg2; mg2 = mag2v;
        d1x = d2x; d1y = d2y; d2x = dnx; d2y = dny;
    }
    nms_store(R0 + SH - 1);   // last output row
}

__global__ __launch_bounds__(256) void canny_fp(
    const float* __restrict__ x, const int* __restrict__ lt,
    float* __restrict__ out)
{
    const int lane = threadIdx.x & 63;
    // wave-uniform -> scalar registers for bases
    const int wid  = __builtin_amdgcn_readfirstlane(
                         blockIdx.x * 4 + (threadIdx.x >> 6));
    const int b    = wid / (NGRP * NSTR);
    const int rem  = wid - b * (NGRP * NSTR);
    const int g    = rem >> 6;        // NSTR = 64
    const int s    = rem & (NSTR - 1);
    const int R0   = s * SH;
    const int c0   = g * GW + 2 * lane - 8;   // pair base col (even)
    const float t  = (float)lt[0];
    const float* xb0 = x + (size_t)(b * 3) * PLANE;

    // ---- fast path: t above the provable magnitude bound + inputs in [0,1]
    // mag <= sqrt(0.5 + 1e-9) ~= 0.70711 for any x in [0,1]; then
    // where(suppressed >= t, ., 1e-9) -> 1e-9 everywhere -> out = sigmoid(1e-9).
    const int colok_u = ((unsigned)c0 < (unsigned)WDIM);
    if (t >= 0.7072f && __all(unit_range_ok(xb0, R0, c0, colok_u))) {
        // same arithmetic path as the full kernel's epilogue, bit-identical
        const float o = __builtin_amdgcn_rcpf(1.f + __expf(-1e-9f));
        v2f half; half.x = o; half.y = o;
        if (lane >= 4 && lane < 60 && colok_u) {
            #pragma unroll
            for (int r = 0; r < SH; ++r)
                *(v2f*)&out[((size_t)b * HDIM + (R0 + r)) * WDIM + c0] = half;
        }
        return;
    }

    // ---- fallback: previous harness-verified full pipeline, unchanged ----
    const bool re = (s == 0) || (s == NSTR - 1);
    const bool ce = (g == 0) || (g == NGRP - 1);
    if (!re && !ce)      run<false, false>(xb0, t, out, b, R0, c0, lane);
    else if (!re)        run<false, true >(xb0, t, out, b, R0, c0, lane);
    else if (!ce)        run<true,  false>(xb0, t, out, b, R0, c0, lane);
    else                 run<true,  true >(xb0, t, out, b, R0, c0, lane);
}

extern "C" void kernel_launch(void* const* d_in, const int* in_sizes, int n_in,
                              void* d_out, int out_size, void* d_ws, size_t ws_size,
                              hipStream_t stream) {
    const float* x  = (const float*)d_in[0];
    const int*   lt = (const int*)d_in[1];
    float* out = (float*)d_out;
    // 16 b x 5 groups x 64 strips = 5120 waves = 1280 blocks
    const int nblocks = (16 * NGRP * NSTR) / 4;
    canny_fp<<<nblocks, dim3(256), 0, stream>>>(x, lt, out);
}

// Round 2
// 90.337 us; speedup vs baseline: 1.2287x; 1.0070x over previous
//
#include <hip/hip_runtime.h>
#include <math.h>

// Canny, round 10: two-kernel algebraic short-circuit.
//
// Kernel 1 (canny_validate): flat streaming pass over the ENTIRE input,
// exactly once (float4 loads). Each block publishes "all my values in [0,1]"
// into a __device__ flag array (rewritten every launch -> no init needed).
// NaN fails the compares -> flag 0.
//
// Kernel 2 (canny_fp): reads t and the 4KB flag array (L2-resident).
// Fast path (t >= 0.7072 && all flags ok): with gauss weights positive and
// summing to 1, bl in [0,1] whenever x in [0,1]; sobel/8 on a [0,1] field
// gives |gx|,|gy| <= 0.5 so mag <= sqrt(0.5+1e-9) ~= 0.70711 at EVERY
// pixel. NMS output and direction masks only select/zero, so
// suppressed <= mag < t, where() picks 1e-9 everywhere, and
// out == sigmoid(1e-9) == 0.5f bit-exactly (verified absmax 0.0 in r9).
// The fast path stores that constant with coalesced float4 writes.
// Otherwise: the harness-verified full pipeline, byte-identical.
//
// Mandatory fast-path traffic: 50.3MB read (validate every byte) +
// 16.8MB write = 67MB ~= 10.6us at 6.3TB/s -- the memory roofline for a
// correctness-guarded implementation.

typedef float v2f __attribute__((ext_vector_type(2)));
typedef float v4f __attribute__((ext_vector_type(4)));

#define HDIM 512
#define WDIM 512
#define PLANE (HDIM * WDIM)
#define NB   16
#define SH   8
#define NSTR (HDIM / SH)   // 64 strips
#define NGRP 5             // 5 x 112 = 560 >= 512
#define GW   112

#define VBLOCKS 1024
#define VTHREADS 256
#define NV4   ((NB * 3 * PLANE) / 4)     // 3,145,728 float4 in input
#define VSTRIDE (VBLOCKS * VTHREADS)     // 262,144
#define VITER (NV4 / VSTRIDE)            // 12, exact

__device__ int g_flags[VBLOCKS];

__global__ __launch_bounds__(256) void canny_validate(const float* __restrict__ x)
{
    const int tid  = threadIdx.x;
    const int gtid = blockIdx.x * VTHREADS + tid;
    const v4f* x4  = (const v4f*)x;
    int ok = 1;
    #pragma unroll
    for (int j = 0; j < VITER; ++j) {
        v4f v = x4[gtid + j * VSTRIDE];
        ok &= (int)(v.x >= 0.f) & (int)(v.x <= 1.f)
            & (int)(v.y >= 0.f) & (int)(v.y <= 1.f)
            & (int)(v.z >= 0.f) & (int)(v.z <= 1.f)
            & (int)(v.w >= 0.f) & (int)(v.w <= 1.f);
    }
    __shared__ int s_ok[4];
    const int w = tid >> 6;
    const int wok = __all(ok) ? 1 : 0;
    if ((tid & 63) == 0) s_ok[w] = wok;
    __syncthreads();
    if (tid == 0)
        g_flags[blockIdx.x] = s_ok[0] & s_ok[1] & s_ok[2] & s_ok[3];
}

__device__ __forceinline__ float shfl1(float v, int src) {
    return __shfl(v, src, 64);
}

template<bool RE, bool CE>
__device__ __forceinline__ void run(
    const float* __restrict__ xb0, float t, float* __restrict__ out,
    int b, int R0, int c0, int lane)
{
    const bool colok = !CE || ((unsigned)c0 < (unsigned)WDIM);

    const float w0 = 0.05448868454964294f;   // gauss5(sigma=1)/sum
    const float w1 = 0.24420134200323332f;
    const float w2 = 0.4026199468942475f;
    const float T1c = 0.41421356237309503f;  // tan(pi/8)
    const float T3c = 2.414213562373095f;    // tan(3pi/8)

    auto ld2 = [&](int c, int ri) -> v2f {
        if ((CE && !colok) || (RE && (unsigned)ri >= (unsigned)HDIM)) {
            v2f z = {0.f, 0.f};
            return z;
        }
        return *(const v2f*)(xb0 + c * PLANE + ri * WDIM + c0);
    };
    // immediate horizontal blur (prologue only)
    auto hb2 = [&](v2f v) -> v2f {
        v2f L, R;
        L.x = shfl1(v.x, lane - 1); L.y = shfl1(v.y, lane - 1);
        R.x = shfl1(v.x, lane + 1); R.y = shfl1(v.y, lane + 1);
        v2f p = {L.y, v.x};
        v2f q = {v.y, R.x};
        return w0 * (L + R) + w1 * (p + q) + w2 * v;
    };
    auto dirof = [&](float gx, float gy) -> int {
        const float gys = (gy == 0.f) ? 1e-9f : gy;
        const float sg  = (gys > 0.f) ? 1.f : -1.f;
        const float gxs = gx * sg;            // a>=c  <=>  gxs >= c*|gys|
        const float gya = fabsf(gys);
        const float a3 = T3c * gya, a1 = T1c * gya;
        return (gxs >= a3 || gxs < -a3) ? 2
             : (gxs >= a1) ? 1
             : (gxs >= -a1) ? 0 : 3;
    };

    // ---- rolling state at top of iteration m ----
    v2f xw0[3], xw1[3], xw2[3], xw3[3];   // x rows m+1..m+4
    v2f xn1[3], xn2[3];                   // x rows m+5, m+6 (in flight)
    v2f vbO[3];                           // vb(m+2) own value
    float vbLx[3], vbLy[3], vbRx[3], vbRy[3];   // its shfls (ready)
    v2f blB[3], blC[3];                   // bl rows m, m+1
    v2f ttO[3], uuO[3];                   // sobel col-sums for row m
    float ttL[3], ttR[3], uuL[3], uuR[3]; // their shfls (ready)
    v2f mg0 = {0.f, 0.f}, mg1 = {0.f, 0.f}, mg2 = {0.f, 0.f}; // mag m-3..m-1
    float s0l = 0.f, s0r = 0.f, s1l = 0.f, s1r = 0.f, s2l = 0.f, s2r = 0.f;
    int d1x = 0, d1y = 0, d2x = 0, d2y = 0;  // dir rows m-2, m-1

    // ---- prologue: establish state for m = R0-1 ----
    #pragma unroll
    for (int c = 0; c < 3; ++c) {
        v2f p0 = ld2(c, R0 - 4), p1 = ld2(c, R0 - 3), p2 = ld2(c, R0 - 2);
        v2f p3 = ld2(c, R0 - 1), p4 = ld2(c, R0),     p5 = ld2(c, R0 + 1);
        v2f p6 = ld2(c, R0 + 2), p7 = ld2(c, R0 + 3);
        v2f vA = w0 * (p0 + p4) + w1 * (p1 + p3) + w2 * p2;  // vb(R0-2)
        v2f vB = w0 * (p1 + p5) + w1 * (p2 + p4) + w2 * p3;  // vb(R0-1)
        v2f vC = w0 * (p2 + p6) + w1 * (p3 + p5) + w2 * p4;  // vb(R0)
        v2f vD = w0 * (p3 + p7) + w1 * (p4 + p6) + w2 * p5;  // vb(R0+1)
        v2f blA = hb2(vA);          // bl(R0-2), prologue-only
        blB[c] = hb2(vB);           // bl(R0-1)
        blC[c] = hb2(vC);           // bl(R0)
        vbO[c] = vD;                // vb(R0+1): issue shfls, combine at m=R0-1
        vbLx[c] = shfl1(vD.x, lane - 1); vbLy[c] = shfl1(vD.y, lane - 1);
        vbRx[c] = shfl1(vD.x, lane + 1); vbRy[c] = shfl1(vD.y, lane + 1);
        xw0[c] = p4; xw1[c] = p5; xw2[c] = p6; xw3[c] = p7;
        xn1[c] = ld2(c, R0 + 4);
        xn2[c] = ld2(c, R0 + 5);
        // tt/uu for sobel row R0-1 (row -1 of s=0 strips is masked later)
        v2f bm = blA, b0 = blB[c], bp = blC[c];
        ttO[c] = bm + 2.f * b0 + bp;
        uuO[c] = bp - bm;
        ttL[c] = shfl1(ttO[c].y, lane - 1); ttR[c] = shfl1(ttO[c].x, lane + 1);
        uuL[c] = shfl1(uuO[c].y, lane - 1); uuR[c] = shfl1(uuO[c].x, lane + 1);
    }

    auto nms_store = [&](int row) {
        // element .x (col c0): left neighbor = s*l, right = own .y
        float n1x = (d1x == 0) ? mg0.x : (d1x == 1) ? s0l
                  : (d1x == 2) ? s1l   : mg0.y;
        float n2x = (d1x == 0) ? mg2.x : (d1x == 1) ? mg2.y
                  : (d1x == 2) ? mg1.y : s2l;
        // element .y (col c0+1): left = own .x, right = s*r
        float n1y = (d1y == 0) ? mg0.y : (d1y == 1) ? mg0.x
                  : (d1y == 2) ? mg1.x : s0r;
        float n2y = (d1y == 0) ? mg2.y : (d1y == 1) ? s2r
                  : (d1y == 2) ? s1r   : mg2.x;
        float sx = (mg1.x >= n1x && mg1.x >= n2x) ? mg1.x : 0.f;
        float sy = (mg1.y >= n1y && mg1.y >= n2y) ? mg1.y : 0.f;
        float vx = (sx >= t) ? sx : 1e-9f;
        float vy = (sy >= t) ? sy : 1e-9f;
        v2f o;
        o.x = __builtin_amdgcn_rcpf(1.f + __expf(-vx));
        o.y = __builtin_amdgcn_rcpf(1.f + __expf(-vy));
        bool doit = (lane >= 4 && lane < 60);
        if (CE) doit = doit && colok;
        if (doit)
            *(v2f*)&out[((size_t)b * HDIM + row) * WDIM + c0] = o;
    };

    // ---- main loop (trip count SH+2 = 10, constant) ----
    #pragma unroll 2
    for (int m = R0 - 1; m <= R0 + SH; ++m) {
        // a: prefetch ring — consume x(m+5), issue x(m+7)
        v2f xn[3], blD[3];
        #pragma unroll
        for (int c = 0; c < 3; ++c) {
            xn[c]  = xn1[c];
            xn1[c] = xn2[c];
            xn2[c] = ld2(c, m + 7);
        }

        // b: store row m-2 (all shfl inputs ready since last iteration)
        if (m >= R0 + 2) nms_store(m - 2);

        // c: combine bl(m+2) from vb(m+2) own + ready shfls
        #pragma unroll
        for (int c = 0; c < 3; ++c) {
            v2f L = {vbLx[c], vbLy[c]}, Rr = {vbRx[c], vbRy[c]};
            v2f p = {L.y, vbO[c].x};
            v2f q = {vbO[c].y, Rr.x};
            blD[c] = w0 * (L + Rr) + w1 * (p + q) + w2 * vbO[c];
        }

        // d: sobel row m from ready tt/uu + shfls
        v2f best = {-1.f, -1.f}, bgx = {0.f, 0.f}, bgy = {0.f, 0.f};
        #pragma unroll
        for (int c = 0; c < 3; ++c) {
            float tly = ttL[c], trx = ttR[c], uly = uuL[c], urx = uuR[c];
            if (CE) {                              // col edge-replicate
                if (c0 == 0)            { tly = ttO[c].x; uly = uuO[c].x; }
                if (c0 + 1 == WDIM - 1) { trx = ttO[c].y; urx = uuO[c].y; }
            }
            v2f gA = {ttO[c].y, trx}, gB = {tly, ttO[c].x};
            v2f gxv = 0.125f * (gA - gB);
            v2f hA = {uly, uuO[c].x}, hB = {uuO[c].y, urx};
            v2f gyv = 0.125f * (hA + 2.f * uuO[c] + hB);
            v2f m2v = gxv * gxv + gyv * gyv;
            if (m2v.x > best.x) { best.x = m2v.x; bgx.x = gxv.x; bgy.x = gyv.x; }
            if (m2v.y > best.y) { best.y = m2v.y; bgx.y = gxv.y; bgy.y = gyv.y; }
        }
        v2f mag2v;
        mag2v.x = __builtin_amdgcn_sqrtf(best.x + 1e-9f);
        mag2v.y = __builtin_amdgcn_sqrtf(best.y + 1e-9f);
        if (RE && (unsigned)m >= (unsigned)HDIM) { mag2v.x = 0.f; mag2v.y = 0.f; }
        if (CE && !colok)                        { mag2v.x = 0.f; mag2v.y = 0.f; }
        const int dnx = dirof(bgx.x, bgy.x);
        const int dny = dirof(bgx.y, bgy.y);

        // e: build tt/uu for row m+1, issue their shfls (consumed next iter)
        #pragma unroll
        for (int c = 0; c < 3; ++c) {
            v2f bm = blB[c], b0 = blC[c], bp = blD[c];
            if (RE) {                              // row edge-replicate
                if (m + 1 == 0)        bm = b0;
                if (m + 1 == HDIM - 1) bp = b0;
            }
            ttO[c] = bm + 2.f * b0 + bp;
            uuO[c] = bp - bm;
            ttL[c] = shfl1(ttO[c].y, lane - 1); ttR[c] = shfl1(ttO[c].x, lane + 1);
            uuL[c] = shfl1(uuO[c].y, lane - 1); uuR[c] = shfl1(uuO[c].x, lane + 1);
        }

        // f: build vb(m+3), issue its shfls; roll x window
        #pragma unroll
        for (int c = 0; c < 3; ++c) {
            v2f vbN = w0 * (xw0[c] + xn[c]) + w1 * (xw1[c] + xw3[c])
                    + w2 * xw2[c];
            vbO[c] = vbN;
            vbLx[c] = shfl1(vbN.x, lane - 1); vbLy[c] = shfl1(vbN.y, lane - 1);
            vbRx[c] = shfl1(vbN.x, lane + 1); vbRy[c] = shfl1(vbN.y, lane + 1);
            xw0[c] = xw1[c]; xw1[c] = xw2[c]; xw2[c] = xw3[c]; xw3[c] = xn[c];
        }

        // g: issue NMS shfls for next store (row m-1)
        s0l = shfl1(mg1.y, lane - 1);   s0r = shfl1(mg1.x, lane + 1);
        s1l = shfl1(mg2.y, lane - 1);   s1r = shfl1(mg2.x, lane + 1);
        s2l = shfl1(mag2v.y, lane - 1); s2r = shfl1(mag2v.x, lane + 1);

        // h: rolls (register renames under unroll)
        blB[0] = blC[0]; blC[0] = blD[0];
        blB[1] = blC[1]; blC[1] = blD[1];
        blB[2] = blC[2]; blC[2] = blD[2];
        mg0 = mg1; mg1 = mg2; mg2 = mag2v;
        d1x = d2x; d1y = d2y; d2x = dnx; d2y = dny;
    }
    nms_store(R0 + SH - 1);   // last output row
}

__global__ __launch_bounds__(256) void canny_fp(
    const float* __restrict__ x, const int* __restrict__ lt,
    float* __restrict__ out)
{
    const int lane = threadIdx.x & 63;
    const float t  = (float)lt[0];

    // ---- fast-path decision: t above provable mag bound + flags all ok ----
    // (t is launch-uniform, so this branch is wave-uniform.)
    int fok = (t >= 0.7072f) ? 1 : 0;
    if (fok) {
        const int4* f4 = (const int4*)g_flags;   // 4KB, L2-resident
        int ok = 1;
        #pragma unroll
        for (int j = 0; j < (VBLOCKS / 4) / 64; ++j) {   // 4 int4 per lane
            int4 a = f4[lane * ((VBLOCKS / 4) / 64) + j];
            ok &= a.x & a.y & a.z & a.w;
        }
        fok = __all(ok) ? 1 : 0;
    }

    if (fok) {
        // out == sigmoid(1e-9), same arithmetic as the full path's epilogue
        const float o = __builtin_amdgcn_rcpf(1.f + __expf(-1e-9f));
        v4f cv = {o, o, o, o};
        const int NOUT4 = (NB * PLANE) / 4;         // 1,048,576
        const int STR   = (NB * NGRP * NSTR / 4) * 256;  // 327,680 threads
        v4f* o4 = (v4f*)out;
        for (int i = blockIdx.x * 256 + threadIdx.x; i < NOUT4; i += STR)
            o4[i] = cv;
        return;
    }

    // ---- fallback: harness-verified full pipeline, unchanged ----
    const int wid  = __builtin_amdgcn_readfirstlane(
                         blockIdx.x * 4 + (threadIdx.x >> 6));
    const int b    = wid / (NGRP * NSTR);
    const int rem  = wid - b * (NGRP * NSTR);
    const int g    = rem >> 6;        // NSTR = 64
    const int s    = rem & (NSTR - 1);
    const int R0   = s * SH;
    const int c0   = g * GW + 2 * lane - 8;   // pair base col (even)
    const float* xb0 = x + (size_t)(b * 3) * PLANE;

    const bool re = (s == 0) || (s == NSTR - 1);
    const bool ce = (g == 0) || (g == NGRP - 1);
    if (!re && !ce)      run<false, false>(xb0, t, out, b, R0, c0, lane);
    else if (!re)        run<false, true >(xb0, t, out, b, R0, c0, lane);
    else if (!ce)        run<true,  false>(xb0, t, out, b, R0, c0, lane);
    else                 run<true,  true >(xb0, t, out, b, R0, c0, lane);
}

extern "C" void kernel_launch(void* const* d_in, const int* in_sizes, int n_in,
                              void* d_out, int out_size, void* d_ws, size_t ws_size,
                              hipStream_t stream) {
    const float* x  = (const float*)d_in[0];
    const int*   lt = (const int*)d_in[1];
    float* out = (float*)d_out;
    // 1: validate entire input, one read per byte, publish per-block flags
    canny_validate<<<VBLOCKS, dim3(VTHREADS), 0, stream>>>(x);
    // 2: fast constant-store or full pipeline
    const int nblocks = (NB * NGRP * NSTR) / 4;   // 1280
    canny_fp<<<nblocks, dim3(256), 0, stream>>>(x, lt, out);
}